// Round 4
// baseline (10.429 us; speedup 1.0000x reference)
//
#include <hip/hip_runtime.h>
#include <math.h>

#define PPD 63                    // (128-4)/2 + 1
#define PW  32                    // patch-pairs per row: ceil(63/2)
#define TOT (64*PPD*PW)           // 129024 threads (2 patches each, last col single)

// z for one 4x4 patch given its 16 angles + uniform weight-trig tables
__device__ __forceinline__ float4 patch_z(const float th[16],
                                          const float uA[4][2],
                                          const float uB[4][2],
                                          const float uR[4][2]) {
    float p0[4], p1[4], dr[4], mr[4], mi[4];
    #pragma unroll
    for (int q = 0; q < 3; ++q) {           // qubits 0..2: RZ,RY,RZ,RY,RZ
        float s0,c0,s1,c1,s2,c2,s3,c3,s4,c4;
        __sincosf(       th[q*5+0], &s0, &c0);
        __sincosf(0.5f * th[q*5+1], &s1, &c1);
        __sincosf(       th[q*5+2], &s2, &c2);
        __sincosf(0.5f * th[q*5+3], &s3, &c3);
        __sincosf(       th[q*5+4], &s4, &c4);
        const float v0x = c1 - s1*c0, v0y = -s1*s0;
        const float v1x = s1 + c1*c0, v1y =  c1*s0;
        const float w1x = v1x*c2 - v1y*s2, w1y = v1x*s2 + v1y*c2;
        const float n0x = c3*v0x - s3*w1x, n0y = c3*v0y - s3*w1y;
        const float n1x = s3*v0x + c3*w1x, n1y = s3*v0y + c3*w1y;
        const float f1x = n1x*c4 - n1y*s4, f1y = n1x*s4 + n1y*c4;
        const float P0 = n0x*n0x + n0y*n0y;
        const float P1 = f1x*f1x + f1y*f1y;
        p0[q] = P0; p1[q] = P1; dr[q] = P0 - P1;
        mr[q] = n0x*f1x + n0y*f1y;
        mi[q] = n0x*f1y - n0y*f1x;
    }
    {   // qubit 3: only RZ(th15): raw state (1, e^{i th})
        float s, c; __sincosf(th[15], &s, &c);
        p0[3] = 1.f; p1[3] = 1.f; dr[3] = 0.f;
        mr[3] = c;   mi[3] = s;
    }
    float z[4];
    #pragma unroll
    for (int q = 0; q < 4; ++q) {
        const int qn = (q + 1) & 3;
        const int j  = (q + 3) & 3;
        const float as_ = dr[qn] * uA[q][1];
        const float br  = p0[j] + p1[j] * uB[j][0];
        const float bi  = p1[j] * uB[j][1];
        const float chw = uA[q][0];
        const float re  = mr[q]*chw + mi[q]*as_;
        const float im  = mi[q]*chw - mr[q]*as_;
        z[q] = uR[q][0]*dr[q] - uR[q][1]*(re*br - im*bi);
    }
    return make_float4(z[0], z[1], z[2], z[3]);
}

__global__ void __launch_bounds__(256)
quanv_kernel(const float* __restrict__ X, const float* __restrict__ W,
             float* __restrict__ out) {
    __shared__ float uA[4][2];   // cos(W[q]/2), 0.5*sin(W[q]/2)
    __shared__ float uB[4][2];   // cos(W[q]),   sin(W[q])
    __shared__ float uR[4][2];   // 0.5*cos(W[4+q]), 0.5*sin(W[4+q])

    const int lt = threadIdx.x;
    if (lt < 4) {
        float s, c;
        __sincosf(0.5f * W[lt], &s, &c);
        uA[lt][0] = c;        uA[lt][1] = 0.5f * s;
        __sincosf(W[lt], &s, &c);
        uB[lt][0] = c;        uB[lt][1] = s;
        __sincosf(W[4 + lt], &s, &c);
        uR[lt][0] = 0.5f * c; uR[lt][1] = 0.5f * s;
    }
    __syncthreads();

    const int tid = blockIdx.x * 256 + lt;
    if (tid >= TOT) return;

    const int b   = tid / (PPD * PW);
    const int rem = tid - b * (PPD * PW);
    const int r   = rem / PW;
    const int pc  = rem - r * PW;
    const int c0  = pc * 2;              // patches c0 and c0+1

    // rows are 16B-aligned at col 4*pc
    const float* xb = X + b * (128 * 128) + (r * 2) * 128 + pc * 4;
    const int hoff = (pc < PW - 1) ? 4 : 0;   // clamp last pair in-bounds
    float4 lo[4]; float2 hi[4];
    #pragma unroll
    for (int i = 0; i < 4; ++i) {
        lo[i] = *reinterpret_cast<const float4*>(xb + i * 128);
        hi[i] = *reinterpret_cast<const float2*>(xb + i * 128 + hoff);
    }

    const int obase = b * (PPD * PPD) + r * PPD + c0;

    {   // patch A: cols 2c0 .. 2c0+3
        float th[16];
        #pragma unroll
        for (int i = 0; i < 4; ++i) {
            th[i*4+0] = lo[i].x; th[i*4+1] = lo[i].y;
            th[i*4+2] = lo[i].z; th[i*4+3] = lo[i].w;
        }
        reinterpret_cast<float4*>(out)[obase] = patch_z(th, uA, uB, uR);
    }
    if (pc < PW - 1) {   // patch B: cols 2c0+2 .. 2c0+5
        float th[16];
        #pragma unroll
        for (int i = 0; i < 4; ++i) {
            th[i*4+0] = lo[i].z; th[i*4+1] = lo[i].w;
            th[i*4+2] = hi[i].x; th[i*4+3] = hi[i].y;
        }
        reinterpret_cast<float4*>(out)[obase + 1] = patch_z(th, uA, uB, uR);
    }
}

extern "C" void kernel_launch(void* const* d_in, const int* in_sizes, int n_in,
                              void* d_out, int out_size, void* d_ws, size_t ws_size,
                              hipStream_t stream) {
    const float* X = (const float*)d_in[0];   // (64,1,128,128) f32
    const float* W = (const float*)d_in[1];   // (1,8) f32
    float* out = (float*)d_out;               // (64,4,63,63) f32

    const int blocks = (TOT + 255) / 256;     // 504
    quanv_kernel<<<dim3(blocks), dim3(256), 0, stream>>>(X, W, out);
}

// Round 5
// 10.057 us; speedup vs baseline: 1.0370x; 1.0370x over previous
//
#include <hip/hip_runtime.h>
#include <math.h>

#define PPD 63                   // (128-4)/2 + 1
#define TOTAL (64*PPD*PPD)       // 254016 patches

__global__ void __launch_bounds__(256)
quanv_kernel(const float* __restrict__ X, const float* __restrict__ W,
             float* __restrict__ out) {
    // Weight-only (uniform) trig, once per block, broadcast via LDS.
    __shared__ float uA[4][2];   // cos(W[q]/2), 0.5*sin(W[q]/2)   (CRZ "A" factor)
    __shared__ float uB[4][2];   // cos(W[q]),   sin(W[q])         (CRZ "B" factor)
    __shared__ float uR[4][2];   // 0.5*cos(W[4+q]), 0.5*sin(W[4+q]) (final-RY fold)

    const int lt = threadIdx.x;
    if (lt < 4) {
        float s, c;
        __sincosf(0.5f * W[lt], &s, &c);
        uA[lt][0] = c;        uA[lt][1] = 0.5f * s;
        __sincosf(W[lt], &s, &c);
        uB[lt][0] = c;        uB[lt][1] = s;
        __sincosf(W[4 + lt], &s, &c);
        uR[lt][0] = 0.5f * c; uR[lt][1] = 0.5f * s;
    }
    __syncthreads();

    const int tid = blockIdx.x * 256 + lt;
    if (tid >= TOTAL) return;

    const int b  = tid / (PPD * PPD);
    const int rc = tid - b * (PPD * PPD);
    const int r  = rc / PPD;
    const int c  = rc - r * PPD;

    // ---- gather 4x4 patch (rows 8B-aligned: even element offset) ----
    const float2* xp = reinterpret_cast<const float2*>(
        X + b * (128 * 128) + (r * 2) * 128 + (c * 2));
    float th[16];
    #pragma unroll
    for (int i = 0; i < 4; ++i) {
        const float2 lo = xp[i * 64];
        const float2 hi = xp[i * 64 + 1];
        th[i*4+0] = lo.x; th[i*4+1] = lo.y;
        th[i*4+2] = hi.x; th[i*4+3] = hi.y;
    }

    // ---- per-qubit chains (phase-factored RZ ~ diag(1,e^{it})), raw norm^2 = 2 ----
    float p0[4], p1[4], dr[4], mr[4], mi[4];
    #pragma unroll
    for (int q = 0; q < 3; ++q) {           // qubits 0..2: RZ,RY,RZ,RY,RZ
        float s0,c0,s1,c1,s2,c2,s3,c3,s4,c4;
        __sincosf(       th[q*5+0], &s0, &c0);
        __sincosf(0.5f * th[q*5+1], &s1, &c1);
        __sincosf(       th[q*5+2], &s2, &c2);
        __sincosf(0.5f * th[q*5+3], &s3, &c3);
        __sincosf(       th[q*5+4], &s4, &c4);
        // start (1,0),(c0,s0); RY(t1)
        const float v0x = c1 - s1*c0, v0y = -s1*s0;
        const float v1x = s1 + c1*c0, v1y =  c1*s0;
        // RZ(t2) on v1
        const float w1x = v1x*c2 - v1y*s2, w1y = v1x*s2 + v1y*c2;
        // RY(t3)
        const float n0x = c3*v0x - s3*w1x, n0y = c3*v0y - s3*w1y;
        const float n1x = s3*v0x + c3*w1x, n1y = s3*v0y + c3*w1y;
        // RZ(t4) on v1 (phase only affects m via v1)
        const float f1x = n1x*c4 - n1y*s4, f1y = n1x*s4 + n1y*c4;
        // per-qubit raw stats
        const float P0 = n0x*n0x + n0y*n0y;
        const float P1 = f1x*f1x + f1y*f1y;
        p0[q] = P0; p1[q] = P1; dr[q] = P0 - P1;
        mr[q] = n0x*f1x + n0y*f1y;          // Re(conj(v0)*v1)
        mi[q] = n0x*f1y - n0y*f1x;          // Im(conj(v0)*v1)
    }
    {   // qubit 3: only RZ(th15): raw state (1, e^{i th}) -> closed-form stats
        float s, c; __sincosf(th[15], &s, &c);
        p0[3] = 1.f; p1[3] = 1.f; dr[3] = 0.f;
        mr[3] = c;   mi[3] = s;
    }

    // ---- z_q = 0.5cos(wry)*d_q - 0.5sin(wry)*Re[m_q * A_q * B_q] ----
    // A_q = (cos(w_q/2), -d_{q+1}*0.5sin(w_q/2));  B_q = P_{q-1,0} + P_{q-1,1} e^{i w_{q-1}}
    float z[4];
    #pragma unroll
    for (int q = 0; q < 4; ++q) {
        const int qn = (q + 1) & 3;          // A uses d of qubit q+1
        const int j  = (q + 3) & 3;          // B uses qubit q-1 and weight W[q-1]
        const float as_ = dr[qn] * uA[q][1];          // = -Im(A_q)
        const float br  = p0[j] + p1[j] * uB[j][0];
        const float bi  = p1[j] * uB[j][1];
        const float chw = uA[q][0];
        const float re  = mr[q]*chw + mi[q]*as_;      // Re(m*A)
        const float im  = mi[q]*chw - mr[q]*as_;      // Im(m*A)
        z[q] = uR[q][0]*dr[q] - uR[q][1]*(re*br - im*bi);
    }

    reinterpret_cast<float4*>(out)[tid] = make_float4(z[0], z[1], z[2], z[3]);
}

extern "C" void kernel_launch(void* const* d_in, const int* in_sizes, int n_in,
                              void* d_out, int out_size, void* d_ws, size_t ws_size,
                              hipStream_t stream) {
    const float* X = (const float*)d_in[0];   // (64,1,128,128) f32
    const float* W = (const float*)d_in[1];   // (1,8) f32
    float* out = (float*)d_out;               // (64,4,63,63) f32

    const int blocks = (TOTAL + 255) / 256;   // 993
    quanv_kernel<<<dim3(blocks), dim3(256), 0, stream>>>(X, W, out);
}